// Round 9
// baseline (181.548 us; speedup 1.0000x reference)
//
#include <hip/hip_runtime.h>
#include <hip/hip_bf16.h>
#include <cstdint>

#define B_BAGS 4096
#define L_LOOK 64
#define NT 4
#define V_ROWS 500000
#define D_EMB 128
#define FEAT 640

typedef _Float16 half8 __attribute__((ext_vector_type(8)));
typedef _Float16 half4 __attribute__((ext_vector_type(4)));
typedef float f32x4 __attribute__((ext_vector_type(4)));

#define GLOAD_LDS(g, l) __builtin_amdgcn_global_load_lds( \
    (const __attribute__((address_space(1))) void*)(g),   \
    (__attribute__((address_space(3))) void*)(l), 16, 0, 0)

// ---------------------------------------------------------------------------
// fp16 GEMM body (fp16 operands in HBM): global_load_lds width 16,
// XOR-swizzled LDS (slot c of row r lives at slot c^(r&7)).
// 4 waves 2x2; wave tile (BM/2)x(BN/2); MFMA 16x16x32 f16; BK=64.
// ---------------------------------------------------------------------------
template<int BM, int BN, bool RELU>
__device__ __forceinline__ void gemm_body(
    _Float16* lds, int bm, int bn,
    const _Float16* __restrict__ X, int ldx,
    const _Float16* __restrict__ W, int ldw,
    const float* __restrict__ bias,
    _Float16* __restrict__ Y, int ldy, int K)
{
    constexpr int BK = 64;
    constexpr int FM = BM / 32;
    constexpr int FN = BN / 32;
    constexpr int AI = BM * 8 / 256;
    constexpr int BI = BN * 8 / 256;

    _Float16* As = lds;
    _Float16* Bs = lds + BM * BK;

    const int tid  = threadIdx.x;
    const int lane = tid & 63;
    const int wave = tid >> 6;
    const int wm   = wave >> 1;
    const int wn   = wave & 1;
    const int q    = lane >> 4;
    const int r16  = lane & 15;

    f32x4 acc[FM][FN] = {};

    for (int k0 = 0; k0 < K; k0 += BK) {
#pragma unroll
        for (int i = 0; i < AI; ++i) {
            int L = i * 256 + tid;
            int row = L >> 3, sl = L & 7;
            const _Float16* src = X + (size_t)(bm + row) * ldx + k0 + ((sl ^ (row & 7)) * 8);
            GLOAD_LDS(src, As + (size_t)(i * 256 + wave * 64) * 8);
        }
#pragma unroll
        for (int j = 0; j < BI; ++j) {
            int L = j * 256 + tid;
            int row = L >> 3, sl = L & 7;
            const _Float16* src = W + (size_t)(bn + row) * ldw + k0 + ((sl ^ (row & 7)) * 8);
            GLOAD_LDS(src, Bs + (size_t)(j * 256 + wave * 64) * 8);
        }
        __syncthreads();

#pragma unroll
        for (int s = 0; s < 2; ++s) {
            half8 a[FM], b[FN];
#pragma unroll
            for (int i = 0; i < FM; ++i) {
                int R = wm * (BM / 2) + i * 16 + r16;
                int sl = (s * 4 + q) ^ (R & 7);
                a[i] = *(const half8*)(As + R * BK + sl * 8);
            }
#pragma unroll
            for (int j = 0; j < FN; ++j) {
                int R = wn * (BN / 2) + j * 16 + r16;
                int sl = (s * 4 + q) ^ (R & 7);
                b[j] = *(const half8*)(Bs + R * BK + sl * 8);
            }
#pragma unroll
            for (int i = 0; i < FM; ++i)
#pragma unroll
                for (int j = 0; j < FN; ++j)
                    acc[i][j] = __builtin_amdgcn_mfma_f32_16x16x32_f16(
                        a[i], b[j], acc[i][j], 0, 0, 0);
        }
        __syncthreads();
    }

#pragma unroll
    for (int i = 0; i < FM; ++i) {
        const int m0 = bm + wm * (BM / 2) + i * 16 + q * 4;
#pragma unroll
        for (int j = 0; j < FN; ++j) {
            const int n = bn + wn * (BN / 2) + j * 16 + r16;
            const float bv = bias[n];
#pragma unroll
            for (int e = 0; e < 4; ++e) {
                float o = acc[i][j][e] + bv;
                if (RELU) o = fmaxf(o, 0.f);
                Y[(size_t)(m0 + e) * ldy + n] = (_Float16)o;
            }
        }
    }
}

// ---------------------------------------------------------------------------
// fp32-input GEMM body: register-staged fp32->fp16 cvt + swizzled ds_write.
// Same LDS layout/swizzle as gemm_body. For gemm1 only (x_dense/bw0 fit L3).
// ---------------------------------------------------------------------------
template<int BM, int BN, bool RELU>
__device__ __forceinline__ void gemm_body_f32(
    _Float16* lds, int bm, int bn,
    const float* __restrict__ X, int ldx,
    const float* __restrict__ W, int ldw,
    const float* __restrict__ bias,
    _Float16* __restrict__ Y, int ldy, int K)
{
    constexpr int BK = 64;
    constexpr int FM = BM / 32;
    constexpr int FN = BN / 32;
    constexpr int AI = BM * 8 / 256;
    constexpr int BI = BN * 8 / 256;

    _Float16* As = lds;
    _Float16* Bs = lds + BM * BK;

    const int tid  = threadIdx.x;
    const int lane = tid & 63;
    const int wave = tid >> 6;
    const int wm   = wave >> 1;
    const int wn   = wave & 1;
    const int q    = lane >> 4;
    const int r16  = lane & 15;

    f32x4 acc[FM][FN] = {};

    for (int k0 = 0; k0 < K; k0 += BK) {
#pragma unroll
        for (int i = 0; i < AI; ++i) {
            int S = i * 256 + tid;
            int row = S >> 3, c = S & 7;
            const float* src = X + (size_t)(bm + row) * ldx + k0 + c * 8;
            float4 v0 = *(const float4*)src;
            float4 v1 = *(const float4*)(src + 4);
            half8 h = { (_Float16)v0.x, (_Float16)v0.y, (_Float16)v0.z, (_Float16)v0.w,
                        (_Float16)v1.x, (_Float16)v1.y, (_Float16)v1.z, (_Float16)v1.w };
            *(half8*)(As + row * BK + ((c ^ (row & 7)) * 8)) = h;
        }
#pragma unroll
        for (int j = 0; j < BI; ++j) {
            int S = j * 256 + tid;
            int row = S >> 3, c = S & 7;
            const float* src = W + (size_t)(bn + row) * ldw + k0 + c * 8;
            float4 v0 = *(const float4*)src;
            float4 v1 = *(const float4*)(src + 4);
            half8 h = { (_Float16)v0.x, (_Float16)v0.y, (_Float16)v0.z, (_Float16)v0.w,
                        (_Float16)v1.x, (_Float16)v1.y, (_Float16)v1.z, (_Float16)v1.w };
            *(half8*)(Bs + row * BK + ((c ^ (row & 7)) * 8)) = h;
        }
        __syncthreads();

#pragma unroll
        for (int s = 0; s < 2; ++s) {
            half8 a[FM], b[FN];
#pragma unroll
            for (int i = 0; i < FM; ++i) {
                int R = wm * (BM / 2) + i * 16 + r16;
                int sl = (s * 4 + q) ^ (R & 7);
                a[i] = *(const half8*)(As + R * BK + sl * 8);
            }
#pragma unroll
            for (int j = 0; j < FN; ++j) {
                int R = wn * (BN / 2) + j * 16 + r16;
                int sl = (s * 4 + q) ^ (R & 7);
                b[j] = *(const half8*)(Bs + R * BK + sl * 8);
            }
#pragma unroll
            for (int i = 0; i < FM; ++i)
#pragma unroll
                for (int j = 0; j < FN; ++j)
                    acc[i][j] = __builtin_amdgcn_mfma_f32_16x16x32_f16(
                        a[i], b[j], acc[i][j], 0, 0, 0);
        }
        __syncthreads();
    }

#pragma unroll
    for (int i = 0; i < FM; ++i) {
        const int m0 = bm + wm * (BM / 2) + i * 16 + q * 4;
#pragma unroll
        for (int j = 0; j < FN; ++j) {
            const int n = bn + wn * (BN / 2) + j * 16 + r16;
            const float bv = bias[n];
#pragma unroll
            for (int e = 0; e < 4; ++e) {
                float o = acc[i][j][e] + bv;
                if (RELU) o = fmaxf(o, 0.f);
                Y[(size_t)(m0 + e) * ldy + n] = (_Float16)o;
            }
        }
    }
}

// ---------------------------------------------------------------------------
// EmbeddingBag body: wave w = table w; float4/lane, 2 rows per instruction.
// ---------------------------------------------------------------------------
__device__ __forceinline__ void emb_body(
    int bag,
    const float* __restrict__ tables,
    const int*   __restrict__ idx,
    _Float16*    __restrict__ feat)
{
    const int wave = threadIdx.x >> 6;
    const int lane = threadIdx.x & 63;
    const int l5   = lane >> 5;
    const int c    = lane & 31;

    const int my_idx = idx[((size_t)bag * L_LOOK + lane) * NT + wave];
    const float* tab = tables + (size_t)wave * V_ROWS * D_EMB;

    float4 acc = {0.f, 0.f, 0.f, 0.f};
#pragma unroll 16
    for (int j = 0; j < 32; ++j) {
        int r = __shfl(my_idx, 2 * j + l5, 64);
        float4 v = ((const float4*)(tab + (size_t)r * D_EMB))[c];
        acc.x += v.x; acc.y += v.y; acc.z += v.z; acc.w += v.w;
    }
    acc.x += __shfl_xor(acc.x, 32, 64);
    acc.y += __shfl_xor(acc.y, 32, 64);
    acc.z += __shfl_xor(acc.z, 32, 64);
    acc.w += __shfl_xor(acc.w, 32, 64);
    if (l5 == 0) {
        half4 h = { (_Float16)acc.x, (_Float16)acc.y, (_Float16)acc.z, (_Float16)acc.w };
        *(half4*)(feat + (size_t)bag * FEAT + D_EMB + wave * D_EMB + c * 4) = h;
    }
}

// ---------------------------------------------------------------------------
// Generic fused dispatch: gemm tiles | emb bags (fp16 gemm path).
// ---------------------------------------------------------------------------
struct GD {
    const _Float16* X; const _Float16* W; const float* bias; _Float16* Y;
    int ldx, ldw, ldy, K, m0, mTiles;
};

__global__ __launch_bounds__(256, 3) void mega(
    GD gA, int nA,
    int embBase, int embCount,
    const float* __restrict__ tables, const int* __restrict__ idx,
    _Float16* __restrict__ feat)
{
    __shared__ __align__(16) _Float16 lds[(128 + 128) * 64];
    int bid = blockIdx.x;
    if (bid < nA) {
        gemm_body<128, 128, true>(lds, gA.m0 + (bid % gA.mTiles) * 128,
                                  (bid / gA.mTiles) * 128,
                                  gA.X, gA.ldx, gA.W, gA.ldw, gA.bias,
                                  gA.Y, gA.ldy, gA.K);
        return;
    }
    bid -= nA;
    emb_body(embBase + bid, tables, idx, feat);
}

// ---------------------------------------------------------------------------
// D1: gemm1 (fp32 inputs, 256 tiles) + cvt of weights + emb bags.
// ---------------------------------------------------------------------------
struct CvtRest {
    const float* src[5];
    _Float16*    dst[5];
    int          n4[5];
};

__global__ __launch_bounds__(256, 3) void fused1(
    const float* __restrict__ X, const float* __restrict__ W,
    const float* __restrict__ bias, _Float16* __restrict__ Y,
    CvtRest cvt,
    const float* __restrict__ tables, const int* __restrict__ idx,
    _Float16* __restrict__ feat)
{
    __shared__ __align__(16) _Float16 lds[(128 + 128) * 64];
    int bid = blockIdx.x;
    if (bid < 256) {
        gemm_body_f32<128, 128, true>(lds, (bid & 31) * 128, (bid >> 5) * 128,
                                      X, 512, W, 512, bias, Y, 1024, 512);
        return;
    }
    bid -= 256;
    if (bid < 64) {
        const int t0 = bid * 256 + threadIdx.x;
        const int stride = 64 * 256;
#pragma unroll
        for (int t = 0; t < 5; ++t) {
            const float4* s = (const float4*)cvt.src[t];
            half4* d = (half4*)cvt.dst[t];
            for (int i = t0; i < cvt.n4[t]; i += stride) {
                float4 v = s[i];
                half4 h = { (_Float16)v.x, (_Float16)v.y, (_Float16)v.z, (_Float16)v.w };
                d[i] = h;
            }
        }
        return;
    }
    emb_body(bid - 64, tables, idx, feat);
}

// ---------------------------------------------------------------------------
// Plain GEMM dispatch (top MLP). BM x BN template tiles.
// ---------------------------------------------------------------------------
template<int BM, int BN, bool RELU>
__global__ __launch_bounds__(256, 3) void gemm_h(
    const _Float16* __restrict__ X, int ldx,
    const _Float16* __restrict__ W, int ldw,
    const float* __restrict__ bias,
    _Float16* __restrict__ Y, int ldy,
    int K)
{
    __shared__ __align__(16) _Float16 lds[(BM + BN) * 64];
    gemm_body<BM, BN, RELU>(lds, blockIdx.y * BM, blockIdx.x * BN,
                            X, ldx, W, ldw, bias, Y, ldy, K);
}

// ---------------------------------------------------------------------------
// top1+top2 fused: 64x128 tile of z1 = relu(z0 @ tw1^T + tb1) computed in
// registers; per-row partial dot with tw2 accumulated via device-scope
// atomics; 8th (last) contributor per row applies bias+sigmoid -> out.
// ---------------------------------------------------------------------------
__global__ __launch_bounds__(256, 3) void top1_fused(
    const _Float16* __restrict__ X,     // z0 [4096,1024]
    const _Float16* __restrict__ W,     // tw1h [512,1024]
    const float* __restrict__ bias,     // tb1
    const _Float16* __restrict__ w2,    // tw2h [512]
    const float* __restrict__ tb2,      // [1]
    float* __restrict__ accb,           // [4096] zeroed
    unsigned int* __restrict__ ctrb,    // [4096] zeroed
    float* __restrict__ out)            // [4096]
{
    constexpr int BM = 64, BN = 128, BK = 64;
    constexpr int FM = BM / 32;   // 2
    constexpr int FN = BN / 32;   // 4
    constexpr int AI = BM * 8 / 256;
    constexpr int BI = BN * 8 / 256;
    const int K = 1024;

    __shared__ __align__(16) _Float16 lds[(BM + BN) * BK];
    _Float16* As = lds;
    _Float16* Bs = lds + BM * BK;

    const int bm = blockIdx.y * BM;
    const int bn = blockIdx.x * BN;
    const int tid  = threadIdx.x;
    const int lane = tid & 63;
    const int wave = tid >> 6;
    const int wm   = wave >> 1;
    const int wn   = wave & 1;
    const int q    = lane >> 4;
    const int r16  = lane & 15;

    f32x4 acc[FM][FN] = {};

    for (int k0 = 0; k0 < K; k0 += BK) {
#pragma unroll
        for (int i = 0; i < AI; ++i) {
            int L = i * 256 + tid;
            int row = L >> 3, sl = L & 7;
            const _Float16* src = X + (size_t)(bm + row) * 1024 + k0 + ((sl ^ (row & 7)) * 8);
            GLOAD_LDS(src, As + (size_t)(i * 256 + wave * 64) * 8);
        }
#pragma unroll
        for (int j = 0; j < BI; ++j) {
            int L = j * 256 + tid;
            int row = L >> 3, sl = L & 7;
            const _Float16* src = W + (size_t)(bn + row) * 1024 + k0 + ((sl ^ (row & 7)) * 8);
            GLOAD_LDS(src, Bs + (size_t)(j * 256 + wave * 64) * 8);
        }
        __syncthreads();

#pragma unroll
        for (int s = 0; s < 2; ++s) {
            half8 a[FM], b[FN];
#pragma unroll
            for (int i = 0; i < FM; ++i) {
                int R = wm * (BM / 2) + i * 16 + r16;
                int sl = (s * 4 + q) ^ (R & 7);
                a[i] = *(const half8*)(As + R * BK + sl * 8);
            }
#pragma unroll
            for (int j = 0; j < FN; ++j) {
                int R = wn * (BN / 2) + j * 16 + r16;
                int sl = (s * 4 + q) ^ (R & 7);
                b[j] = *(const half8*)(Bs + R * BK + sl * 8);
            }
#pragma unroll
            for (int i = 0; i < FM; ++i)
#pragma unroll
                for (int j = 0; j < FN; ++j)
                    acc[i][j] = __builtin_amdgcn_mfma_f32_16x16x32_f16(
                        a[i], b[j], acc[i][j], 0, 0, 0);
        }
        __syncthreads();
    }

    // ---- fused epilogue: z1 = relu(acc + tb1); partial[m] = sum z1*w2 ----
    float part[FM][4];
#pragma unroll
    for (int i = 0; i < FM; ++i)
#pragma unroll
        for (int e = 0; e < 4; ++e) part[i][e] = 0.f;

#pragma unroll
    for (int j = 0; j < FN; ++j) {
        const int n = bn + wn * (BN / 2) + j * 16 + r16;
        const float bv = bias[n];
        const float wv = (float)w2[n];
#pragma unroll
        for (int i = 0; i < FM; ++i)
#pragma unroll
            for (int e = 0; e < 4; ++e) {
                float v = fmaxf(acc[i][j][e] + bv, 0.f);
                part[i][e] += v * wv;
            }
    }
    // reduce over the 16 r16-lanes of each q-group
#pragma unroll
    for (int mask = 1; mask < 16; mask <<= 1) {
#pragma unroll
        for (int i = 0; i < FM; ++i)
#pragma unroll
            for (int e = 0; e < 4; ++e)
                part[i][e] += __shfl_xor(part[i][e], mask, 64);
    }

    if (r16 == 0) {
#pragma unroll
        for (int i = 0; i < FM; ++i)
#pragma unroll
            for (int e = 0; e < 4; ++e) {
                int m = bm + wm * (BM / 2) + i * 16 + q * 4 + e;
                atomicAdd(&accb[m], part[i][e]);
            }
        __threadfence();
#pragma unroll
        for (int i = 0; i < FM; ++i)
#pragma unroll
            for (int e = 0; e < 4; ++e) {
                int m = bm + wm * (BM / 2) + i * 16 + q * 4 + e;
                unsigned int c = atomicAdd(&ctrb[m], 1u);
                if (c == 7u) {   // 4 n-blocks x 2 wn-waves = 8 contributors
                    float tot = atomicAdd(&accb[m], 0.0f);  // coherent read
                    float x = tot + tb2[0];
                    out[m] = 1.f / (1.f + expf(-x));
                }
            }
    }
}

// ---------------------------------------------------------------------------
extern "C" void kernel_launch(void* const* d_in, const int* in_sizes, int n_in,
                              void* d_out, int out_size, void* d_ws, size_t ws_size,
                              hipStream_t stream) {
    const float* x_dense = (const float*)d_in[0];   // [4096,512]
    const float* tables  = (const float*)d_in[1];   // [4,500000,128]
    const float* bw0 = (const float*)d_in[2];
    const float* bb0 = (const float*)d_in[3];
    const float* bw1 = (const float*)d_in[4];
    const float* bb1 = (const float*)d_in[5];
    const float* bw2 = (const float*)d_in[6];
    const float* bb2 = (const float*)d_in[7];
    const float* tw0 = (const float*)d_in[8];
    const float* tb0 = (const float*)d_in[9];
    const float* tw1 = (const float*)d_in[10];
    const float* tb1 = (const float*)d_in[11];
    const float* tw2 = (const float*)d_in[12];
    const float* tb2 = (const float*)d_in[13];
    const int*   x_idx = (const int*)d_in[14];
    float* out = (float*)d_out;

    char* p = (char*)d_ws;
    auto alloc = [&](size_t bytes) {
        char* r = p; p += (bytes + 255) & ~(size_t)255; return r;
    };
    _Float16* bw1h = (_Float16*)alloc((size_t)512 * 1024 * 2);
    _Float16* bw2h = (_Float16*)alloc((size_t)128 * 512 * 2);
    _Float16* tw0h = (_Float16*)alloc((size_t)1024 * 640 * 2);
    _Float16* tw1h = (_Float16*)alloc((size_t)512 * 1024 * 2);
    _Float16* tw2h = (_Float16*)alloc((size_t)512 * 2);
    _Float16* h0h  = (_Float16*)alloc((size_t)4096 * 1024 * 2);
    _Float16* h1h  = (_Float16*)alloc((size_t)4096 * 512 * 2);
    _Float16* feat = (_Float16*)alloc((size_t)4096 * 640 * 2);
    _Float16* z0h  = (_Float16*)alloc((size_t)4096 * 1024 * 2);
    float*        accb = (float*)alloc((size_t)4096 * 4);
    unsigned int* ctrb = (unsigned int*)alloc((size_t)4096 * 4);

    CvtRest cr;
    cr.src[0] = bw1; cr.dst[0] = bw1h; cr.n4[0] = 512 * 1024 / 4;
    cr.src[1] = bw2; cr.dst[1] = bw2h; cr.n4[1] = 128 * 512 / 4;
    cr.src[2] = tw0; cr.dst[2] = tw0h; cr.n4[2] = 1024 * 640 / 4;
    cr.src[3] = tw1; cr.dst[3] = tw1h; cr.n4[3] = 512 * 1024 / 4;
    cr.src[4] = tw2; cr.dst[4] = tw2h; cr.n4[4] = 512 / 4;

    dim3 blk(256);

    // ---- GEMM descriptors ----
    GD g2;  // h0 @ bw1^T -> h1 [4096,512]
    g2.X = h0h; g2.W = bw1h; g2.bias = bb1; g2.Y = h1h;
    g2.ldx = 1024; g2.ldw = 1024; g2.ldy = 512; g2.K = 1024; g2.m0 = 0; g2.mTiles = 32;

    GD g3;  // h1 @ bw2^T -> feat[:,0:128]
    g3.X = h1h; g3.W = bw2h; g3.bias = bb2; g3.Y = feat;
    g3.ldx = 512; g3.ldw = 512; g3.ldy = 640; g3.K = 512; g3.m0 = 0; g3.mTiles = 32;

    // zero the top2 accumulator + counters (contiguous 32 KB)
    hipMemsetAsync(accb, 0, (size_t)4096 * 4 * 2, stream);

    // ---- D1: gemm1(fp32 in) + cvt-rest + emb [0,2048) ----
    fused1<<<dim3(256 + 64 + 2048), blk, 0, stream>>>(
        x_dense, bw0, bb0, h0h, cr, tables, x_idx, feat);

    // ---- D2: gemm2 + emb [2048,3328) ----
    mega<<<dim3(128 + 1280), blk, 0, stream>>>(
        g2, 128, 2048, 1280, tables, x_idx, feat);

    // ---- D3: gemm3 + emb [3328,4096) ----
    mega<<<dim3(32 + 768), blk, 0, stream>>>(
        g3, 32, 3328, 768, tables, x_idx, feat);

    // ---- D4: feat @ tw0^T -> z0 [4096,1024]; 64x128 tiles -> 512 blocks ----
    gemm_h<64, 128, true><<<dim3(8, 64), blk, 0, stream>>>(
        feat, 640, tw0h, 640, tb0, z0h, 1024, 640);

    // ---- D5: top1+top2 fused -> out ----
    top1_fused<<<dim3(4, 64), blk, 0, stream>>>(
        z0h, tw1h, tb1, tw2h, tb2, accb, ctrb, out);
}

// Round 10
// 161.383 us; speedup vs baseline: 1.1250x; 1.1250x over previous
//
#include <hip/hip_runtime.h>
#include <hip/hip_bf16.h>
#include <cstdint>

#define B_BAGS 4096
#define L_LOOK 64
#define NT 4
#define V_ROWS 500000
#define D_EMB 128
#define FEAT 640

typedef _Float16 half8 __attribute__((ext_vector_type(8)));
typedef _Float16 half4 __attribute__((ext_vector_type(4)));
typedef float f32x4 __attribute__((ext_vector_type(4)));

#define GLOAD_LDS(g, l) __builtin_amdgcn_global_load_lds( \
    (const __attribute__((address_space(1))) void*)(g),   \
    (__attribute__((address_space(3))) void*)(l), 16, 0, 0)

// ---------------------------------------------------------------------------
// fp16 GEMM body (fp16 operands in HBM): global_load_lds width 16,
// XOR-swizzled LDS (slot c of row r lives at slot c^(r&7)).
// 4 waves 2x2; wave tile (BM/2)x(BN/2); MFMA 16x16x32 f16; BK=64.
// ---------------------------------------------------------------------------
template<int BM, int BN, bool RELU>
__device__ __forceinline__ void gemm_body(
    _Float16* lds, int bm, int bn,
    const _Float16* __restrict__ X, int ldx,
    const _Float16* __restrict__ W, int ldw,
    const float* __restrict__ bias,
    _Float16* __restrict__ Y, int ldy, int K)
{
    constexpr int BK = 64;
    constexpr int FM = BM / 32;
    constexpr int FN = BN / 32;
    constexpr int AI = BM * 8 / 256;
    constexpr int BI = BN * 8 / 256;

    _Float16* As = lds;
    _Float16* Bs = lds + BM * BK;

    const int tid  = threadIdx.x;
    const int lane = tid & 63;
    const int wave = tid >> 6;
    const int wm   = wave >> 1;
    const int wn   = wave & 1;
    const int q    = lane >> 4;
    const int r16  = lane & 15;

    f32x4 acc[FM][FN] = {};

    for (int k0 = 0; k0 < K; k0 += BK) {
#pragma unroll
        for (int i = 0; i < AI; ++i) {
            int L = i * 256 + tid;
            int row = L >> 3, sl = L & 7;
            const _Float16* src = X + (size_t)(bm + row) * ldx + k0 + ((sl ^ (row & 7)) * 8);
            GLOAD_LDS(src, As + (size_t)(i * 256 + wave * 64) * 8);
        }
#pragma unroll
        for (int j = 0; j < BI; ++j) {
            int L = j * 256 + tid;
            int row = L >> 3, sl = L & 7;
            const _Float16* src = W + (size_t)(bn + row) * ldw + k0 + ((sl ^ (row & 7)) * 8);
            GLOAD_LDS(src, Bs + (size_t)(j * 256 + wave * 64) * 8);
        }
        __syncthreads();

#pragma unroll
        for (int s = 0; s < 2; ++s) {
            half8 a[FM], b[FN];
#pragma unroll
            for (int i = 0; i < FM; ++i) {
                int R = wm * (BM / 2) + i * 16 + r16;
                int sl = (s * 4 + q) ^ (R & 7);
                a[i] = *(const half8*)(As + R * BK + sl * 8);
            }
#pragma unroll
            for (int j = 0; j < FN; ++j) {
                int R = wn * (BN / 2) + j * 16 + r16;
                int sl = (s * 4 + q) ^ (R & 7);
                b[j] = *(const half8*)(Bs + R * BK + sl * 8);
            }
#pragma unroll
            for (int i = 0; i < FM; ++i)
#pragma unroll
                for (int j = 0; j < FN; ++j)
                    acc[i][j] = __builtin_amdgcn_mfma_f32_16x16x32_f16(
                        a[i], b[j], acc[i][j], 0, 0, 0);
        }
        __syncthreads();
    }

#pragma unroll
    for (int i = 0; i < FM; ++i) {
        const int m0 = bm + wm * (BM / 2) + i * 16 + q * 4;
#pragma unroll
        for (int j = 0; j < FN; ++j) {
            const int n = bn + wn * (BN / 2) + j * 16 + r16;
            const float bv = bias[n];
#pragma unroll
            for (int e = 0; e < 4; ++e) {
                float o = acc[i][j][e] + bv;
                if (RELU) o = fmaxf(o, 0.f);
                Y[(size_t)(m0 + e) * ldy + n] = (_Float16)o;
            }
        }
    }
}

// ---------------------------------------------------------------------------
// fp32-input GEMM body: register-staged fp32->fp16 cvt + swizzled ds_write.
// Same LDS layout/swizzle as gemm_body. For gemm1 only (x_dense/bw0 fit L3).
// ---------------------------------------------------------------------------
template<int BM, int BN, bool RELU>
__device__ __forceinline__ void gemm_body_f32(
    _Float16* lds, int bm, int bn,
    const float* __restrict__ X, int ldx,
    const float* __restrict__ W, int ldw,
    const float* __restrict__ bias,
    _Float16* __restrict__ Y, int ldy, int K)
{
    constexpr int BK = 64;
    constexpr int FM = BM / 32;
    constexpr int FN = BN / 32;
    constexpr int AI = BM * 8 / 256;
    constexpr int BI = BN * 8 / 256;

    _Float16* As = lds;
    _Float16* Bs = lds + BM * BK;

    const int tid  = threadIdx.x;
    const int lane = tid & 63;
    const int wave = tid >> 6;
    const int wm   = wave >> 1;
    const int wn   = wave & 1;
    const int q    = lane >> 4;
    const int r16  = lane & 15;

    f32x4 acc[FM][FN] = {};

    for (int k0 = 0; k0 < K; k0 += BK) {
#pragma unroll
        for (int i = 0; i < AI; ++i) {
            int S = i * 256 + tid;
            int row = S >> 3, c = S & 7;
            const float* src = X + (size_t)(bm + row) * ldx + k0 + c * 8;
            float4 v0 = *(const float4*)src;
            float4 v1 = *(const float4*)(src + 4);
            half8 h = { (_Float16)v0.x, (_Float16)v0.y, (_Float16)v0.z, (_Float16)v0.w,
                        (_Float16)v1.x, (_Float16)v1.y, (_Float16)v1.z, (_Float16)v1.w };
            *(half8*)(As + row * BK + ((c ^ (row & 7)) * 8)) = h;
        }
#pragma unroll
        for (int j = 0; j < BI; ++j) {
            int S = j * 256 + tid;
            int row = S >> 3, c = S & 7;
            const float* src = W + (size_t)(bn + row) * ldw + k0 + c * 8;
            float4 v0 = *(const float4*)src;
            float4 v1 = *(const float4*)(src + 4);
            half8 h = { (_Float16)v0.x, (_Float16)v0.y, (_Float16)v0.z, (_Float16)v0.w,
                        (_Float16)v1.x, (_Float16)v1.y, (_Float16)v1.z, (_Float16)v1.w };
            *(half8*)(Bs + row * BK + ((c ^ (row & 7)) * 8)) = h;
        }
        __syncthreads();

#pragma unroll
        for (int s = 0; s < 2; ++s) {
            half8 a[FM], b[FN];
#pragma unroll
            for (int i = 0; i < FM; ++i) {
                int R = wm * (BM / 2) + i * 16 + r16;
                int sl = (s * 4 + q) ^ (R & 7);
                a[i] = *(const half8*)(As + R * BK + sl * 8);
            }
#pragma unroll
            for (int j = 0; j < FN; ++j) {
                int R = wn * (BN / 2) + j * 16 + r16;
                int sl = (s * 4 + q) ^ (R & 7);
                b[j] = *(const half8*)(Bs + R * BK + sl * 8);
            }
#pragma unroll
            for (int i = 0; i < FM; ++i)
#pragma unroll
                for (int j = 0; j < FN; ++j)
                    acc[i][j] = __builtin_amdgcn_mfma_f32_16x16x32_f16(
                        a[i], b[j], acc[i][j], 0, 0, 0);
        }
        __syncthreads();
    }

#pragma unroll
    for (int i = 0; i < FM; ++i) {
        const int m0 = bm + wm * (BM / 2) + i * 16 + q * 4;
#pragma unroll
        for (int j = 0; j < FN; ++j) {
            const int n = bn + wn * (BN / 2) + j * 16 + r16;
            const float bv = bias[n];
#pragma unroll
            for (int e = 0; e < 4; ++e) {
                float o = acc[i][j][e] + bv;
                if (RELU) o = fmaxf(o, 0.f);
                Y[(size_t)(m0 + e) * ldy + n] = (_Float16)o;
            }
        }
    }
}

// ---------------------------------------------------------------------------
// EmbeddingBag body: wave w = table w; float4/lane, 2 rows per instruction.
// ---------------------------------------------------------------------------
__device__ __forceinline__ void emb_body(
    int bag,
    const float* __restrict__ tables,
    const int*   __restrict__ idx,
    _Float16*    __restrict__ feat)
{
    const int wave = threadIdx.x >> 6;
    const int lane = threadIdx.x & 63;
    const int l5   = lane >> 5;
    const int c    = lane & 31;

    const int my_idx = idx[((size_t)bag * L_LOOK + lane) * NT + wave];
    const float* tab = tables + (size_t)wave * V_ROWS * D_EMB;

    float4 acc = {0.f, 0.f, 0.f, 0.f};
#pragma unroll 16
    for (int j = 0; j < 32; ++j) {
        int r = __shfl(my_idx, 2 * j + l5, 64);
        float4 v = ((const float4*)(tab + (size_t)r * D_EMB))[c];
        acc.x += v.x; acc.y += v.y; acc.z += v.z; acc.w += v.w;
    }
    acc.x += __shfl_xor(acc.x, 32, 64);
    acc.y += __shfl_xor(acc.y, 32, 64);
    acc.z += __shfl_xor(acc.z, 32, 64);
    acc.w += __shfl_xor(acc.w, 32, 64);
    if (l5 == 0) {
        half4 h = { (_Float16)acc.x, (_Float16)acc.y, (_Float16)acc.z, (_Float16)acc.w };
        *(half4*)(feat + (size_t)bag * FEAT + D_EMB + wave * D_EMB + c * 4) = h;
    }
}

// ---------------------------------------------------------------------------
// Generic fused dispatch: gemm tiles | emb bags (fp16 gemm path).
// ---------------------------------------------------------------------------
struct GD {
    const _Float16* X; const _Float16* W; const float* bias; _Float16* Y;
    int ldx, ldw, ldy, K, m0, mTiles;
};

__global__ __launch_bounds__(256, 3) void mega(
    GD gA, int nA,
    int embBase, int embCount,
    const float* __restrict__ tables, const int* __restrict__ idx,
    _Float16* __restrict__ feat)
{
    __shared__ __align__(16) _Float16 lds[(128 + 128) * 64];
    int bid = blockIdx.x;
    if (bid < nA) {
        gemm_body<128, 128, true>(lds, gA.m0 + (bid % gA.mTiles) * 128,
                                  (bid / gA.mTiles) * 128,
                                  gA.X, gA.ldx, gA.W, gA.ldw, gA.bias,
                                  gA.Y, gA.ldy, gA.K);
        return;
    }
    bid -= nA;
    emb_body(embBase + bid, tables, idx, feat);
}

// ---------------------------------------------------------------------------
// D1: gemm1 (fp32 inputs, 256 tiles) + cvt of weights + emb bags.
// ---------------------------------------------------------------------------
struct CvtRest {
    const float* src[5];
    _Float16*    dst[5];
    int          n4[5];
};

__global__ __launch_bounds__(256, 3) void fused1(
    const float* __restrict__ X, const float* __restrict__ W,
    const float* __restrict__ bias, _Float16* __restrict__ Y,
    CvtRest cvt,
    const float* __restrict__ tables, const int* __restrict__ idx,
    _Float16* __restrict__ feat)
{
    __shared__ __align__(16) _Float16 lds[(128 + 128) * 64];
    int bid = blockIdx.x;
    if (bid < 256) {
        gemm_body_f32<128, 128, true>(lds, (bid & 31) * 128, (bid >> 5) * 128,
                                      X, 512, W, 512, bias, Y, 1024, 512);
        return;
    }
    bid -= 256;
    if (bid < 64) {
        const int t0 = bid * 256 + threadIdx.x;
        const int stride = 64 * 256;
#pragma unroll
        for (int t = 0; t < 5; ++t) {
            const float4* s = (const float4*)cvt.src[t];
            half4* d = (half4*)cvt.dst[t];
            for (int i = t0; i < cvt.n4[t]; i += stride) {
                float4 v = s[i];
                half4 h = { (_Float16)v.x, (_Float16)v.y, (_Float16)v.z, (_Float16)v.w };
                d[i] = h;
            }
        }
        return;
    }
    emb_body(bid - 64, tables, idx, feat);
}

// ---------------------------------------------------------------------------
// Plain GEMM dispatch (top MLP). BM x BN template tiles.
// ---------------------------------------------------------------------------
template<int BM, int BN, bool RELU>
__global__ __launch_bounds__(256, 3) void gemm_h(
    const _Float16* __restrict__ X, int ldx,
    const _Float16* __restrict__ W, int ldw,
    const float* __restrict__ bias,
    _Float16* __restrict__ Y, int ldy,
    int K)
{
    __shared__ __align__(16) _Float16 lds[(BM + BN) * 64];
    gemm_body<BM, BN, RELU>(lds, blockIdx.y * BM, blockIdx.x * BN,
                            X, ldx, W, ldw, bias, Y, ldy, K);
}

// ---------------------------------------------------------------------------
// Final layer: out[m] = sigmoid(dot(z1[m,:512], w) + b), fp16 inputs.
// ---------------------------------------------------------------------------
__global__ __launch_bounds__(256) void top2_h(
    const _Float16* __restrict__ Z,
    const _Float16* __restrict__ w,
    const float* __restrict__ bsc,
    float* __restrict__ out)
{
    const int row  = blockIdx.x * 4 + (threadIdx.x >> 6);
    const int lane = threadIdx.x & 63;

    half8 z  = *(const half8*)(Z + (size_t)row * 512 + lane * 8);
    half8 wv = *(const half8*)(w + lane * 8);
    float s = 0.f;
#pragma unroll
    for (int i = 0; i < 8; ++i) s += (float)z[i] * (float)wv[i];
#pragma unroll
    for (int off = 32; off > 0; off >>= 1) s += __shfl_down(s, off, 64);
    if (lane == 0) {
        float x = s + bsc[0];
        out[row] = 1.f / (1.f + expf(-x));
    }
}

// ---------------------------------------------------------------------------
extern "C" void kernel_launch(void* const* d_in, const int* in_sizes, int n_in,
                              void* d_out, int out_size, void* d_ws, size_t ws_size,
                              hipStream_t stream) {
    const float* x_dense = (const float*)d_in[0];   // [4096,512]
    const float* tables  = (const float*)d_in[1];   // [4,500000,128]
    const float* bw0 = (const float*)d_in[2];
    const float* bb0 = (const float*)d_in[3];
    const float* bw1 = (const float*)d_in[4];
    const float* bb1 = (const float*)d_in[5];
    const float* bw2 = (const float*)d_in[6];
    const float* bb2 = (const float*)d_in[7];
    const float* tw0 = (const float*)d_in[8];
    const float* tb0 = (const float*)d_in[9];
    const float* tw1 = (const float*)d_in[10];
    const float* tb1 = (const float*)d_in[11];
    const float* tw2 = (const float*)d_in[12];
    const float* tb2 = (const float*)d_in[13];
    const int*   x_idx = (const int*)d_in[14];
    float* out = (float*)d_out;

    char* p = (char*)d_ws;
    auto alloc = [&](size_t bytes) {
        char* r = p; p += (bytes + 255) & ~(size_t)255; return r;
    };
    _Float16* bw1h = (_Float16*)alloc((size_t)512 * 1024 * 2);
    _Float16* bw2h = (_Float16*)alloc((size_t)128 * 512 * 2);
    _Float16* tw0h = (_Float16*)alloc((size_t)1024 * 640 * 2);
    _Float16* tw1h = (_Float16*)alloc((size_t)512 * 1024 * 2);
    _Float16* tw2h = (_Float16*)alloc((size_t)512 * 2);
    _Float16* h0h  = (_Float16*)alloc((size_t)4096 * 1024 * 2);
    _Float16* h1h  = (_Float16*)alloc((size_t)4096 * 512 * 2);
    _Float16* feat = (_Float16*)alloc((size_t)4096 * 640 * 2);
    _Float16* z0h  = (_Float16*)alloc((size_t)4096 * 1024 * 2);
    _Float16* z1h  = (_Float16*)alloc((size_t)4096 * 512 * 2);

    CvtRest cr;
    cr.src[0] = bw1; cr.dst[0] = bw1h; cr.n4[0] = 512 * 1024 / 4;
    cr.src[1] = bw2; cr.dst[1] = bw2h; cr.n4[1] = 128 * 512 / 4;
    cr.src[2] = tw0; cr.dst[2] = tw0h; cr.n4[2] = 1024 * 640 / 4;
    cr.src[3] = tw1; cr.dst[3] = tw1h; cr.n4[3] = 512 * 1024 / 4;
    cr.src[4] = tw2; cr.dst[4] = tw2h; cr.n4[4] = 512 / 4;

    dim3 blk(256);

    // ---- GEMM descriptors ----
    GD g2;  // h0 @ bw1^T -> h1 [4096,512]
    g2.X = h0h; g2.W = bw1h; g2.bias = bb1; g2.Y = h1h;
    g2.ldx = 1024; g2.ldw = 1024; g2.ldy = 512; g2.K = 1024; g2.m0 = 0; g2.mTiles = 32;

    GD g3;  // h1 @ bw2^T -> feat[:,0:128]
    g3.X = h1h; g3.W = bw2h; g3.bias = bb2; g3.Y = feat;
    g3.ldx = 512; g3.ldw = 512; g3.ldy = 640; g3.K = 512; g3.m0 = 0; g3.mTiles = 32;

    // ---- D1: gemm1(fp32 in) + cvt-rest + emb [0,2048) ----
    fused1<<<dim3(256 + 64 + 2048), blk, 0, stream>>>(
        x_dense, bw0, bb0, h0h, cr, tables, x_idx, feat);

    // ---- D2: gemm2 + emb [2048,3328) ----
    mega<<<dim3(128 + 1280), blk, 0, stream>>>(
        g2, 128, 2048, 1280, tables, x_idx, feat);

    // ---- D3: gemm3 + emb [3328,4096) ----
    mega<<<dim3(32 + 768), blk, 0, stream>>>(
        g3, 32, 3328, 768, tables, x_idx, feat);

    // ---- D4: feat @ tw0^T -> z0 [4096,1024]; 64x128 tiles -> 512 blocks ----
    gemm_h<64, 128, true><<<dim3(8, 64), blk, 0, stream>>>(
        feat, 640, tw0h, 640, tb0, z0h, 1024, 640);

    // ---- D5: z0 @ tw1^T -> z1 [4096,512]; 64x128 tiles -> 256 blocks ----
    gemm_h<64, 128, true><<<dim3(4, 64), blk, 0, stream>>>(
        z0h, 1024, tw1h, 1024, tb1, z1h, 512, 1024);

    // ---- D6: sigmoid(z1 . tw2 + tb2) ----
    top2_h<<<dim3(1024), blk, 0, stream>>>(z1h, tw2h, tb2, out);
}

// Round 11
// 161.035 us; speedup vs baseline: 1.1274x; 1.0022x over previous
//
#include <hip/hip_runtime.h>
#include <hip/hip_bf16.h>
#include <cstdint>

#define B_BAGS 4096
#define L_LOOK 64
#define NT 4
#define V_ROWS 500000
#define D_EMB 128
#define FEAT 640

typedef _Float16 half8 __attribute__((ext_vector_type(8)));
typedef _Float16 half4 __attribute__((ext_vector_type(4)));
typedef float f32x4 __attribute__((ext_vector_type(4)));

#define GLOAD_LDS(g, l) __builtin_amdgcn_global_load_lds( \
    (const __attribute__((address_space(1))) void*)(g),   \
    (__attribute__((address_space(3))) void*)(l), 16, 0, 0)

// ---------------------------------------------------------------------------
// fp16 GEMM body (fp16 operands in HBM): global_load_lds width 16,
// XOR-swizzled LDS (slot c of row r lives at slot c^(r&7)).
// 4 waves 2x2; wave tile (BM/2)x(BN/2); MFMA 16x16x32 f16; BK=64.
// ---------------------------------------------------------------------------
template<int BM, int BN, bool RELU>
__device__ __forceinline__ void gemm_body(
    _Float16* lds, int bm, int bn,
    const _Float16* __restrict__ X, int ldx,
    const _Float16* __restrict__ W, int ldw,
    const float* __restrict__ bias,
    _Float16* __restrict__ Y, int ldy, int K)
{
    constexpr int BK = 64;
    constexpr int FM = BM / 32;
    constexpr int FN = BN / 32;
    constexpr int AI = BM * 8 / 256;
    constexpr int BI = BN * 8 / 256;

    _Float16* As = lds;
    _Float16* Bs = lds + BM * BK;

    const int tid  = threadIdx.x;
    const int lane = tid & 63;
    const int wave = tid >> 6;
    const int wm   = wave >> 1;
    const int wn   = wave & 1;
    const int q    = lane >> 4;
    const int r16  = lane & 15;

    f32x4 acc[FM][FN] = {};

    for (int k0 = 0; k0 < K; k0 += BK) {
#pragma unroll
        for (int i = 0; i < AI; ++i) {
            int L = i * 256 + tid;
            int row = L >> 3, sl = L & 7;
            const _Float16* src = X + (size_t)(bm + row) * ldx + k0 + ((sl ^ (row & 7)) * 8);
            GLOAD_LDS(src, As + (size_t)(i * 256 + wave * 64) * 8);
        }
#pragma unroll
        for (int j = 0; j < BI; ++j) {
            int L = j * 256 + tid;
            int row = L >> 3, sl = L & 7;
            const _Float16* src = W + (size_t)(bn + row) * ldw + k0 + ((sl ^ (row & 7)) * 8);
            GLOAD_LDS(src, Bs + (size_t)(j * 256 + wave * 64) * 8);
        }
        __syncthreads();

#pragma unroll
        for (int s = 0; s < 2; ++s) {
            half8 a[FM], b[FN];
#pragma unroll
            for (int i = 0; i < FM; ++i) {
                int R = wm * (BM / 2) + i * 16 + r16;
                int sl = (s * 4 + q) ^ (R & 7);
                a[i] = *(const half8*)(As + R * BK + sl * 8);
            }
#pragma unroll
            for (int j = 0; j < FN; ++j) {
                int R = wn * (BN / 2) + j * 16 + r16;
                int sl = (s * 4 + q) ^ (R & 7);
                b[j] = *(const half8*)(Bs + R * BK + sl * 8);
            }
#pragma unroll
            for (int i = 0; i < FM; ++i)
#pragma unroll
                for (int j = 0; j < FN; ++j)
                    acc[i][j] = __builtin_amdgcn_mfma_f32_16x16x32_f16(
                        a[i], b[j], acc[i][j], 0, 0, 0);
        }
        __syncthreads();
    }

#pragma unroll
    for (int i = 0; i < FM; ++i) {
        const int m0 = bm + wm * (BM / 2) + i * 16 + q * 4;
#pragma unroll
        for (int j = 0; j < FN; ++j) {
            const int n = bn + wn * (BN / 2) + j * 16 + r16;
            const float bv = bias[n];
#pragma unroll
            for (int e = 0; e < 4; ++e) {
                float o = acc[i][j][e] + bv;
                if (RELU) o = fmaxf(o, 0.f);
                Y[(size_t)(m0 + e) * ldy + n] = (_Float16)o;
            }
        }
    }
}

// ---------------------------------------------------------------------------
// fp32-input GEMM body: register-staged fp32->fp16 cvt + swizzled ds_write.
// Same LDS layout/swizzle as gemm_body. For gemm1 only (x_dense/bw0 fit L3).
// ---------------------------------------------------------------------------
template<int BM, int BN, bool RELU>
__device__ __forceinline__ void gemm_body_f32(
    _Float16* lds, int bm, int bn,
    const float* __restrict__ X, int ldx,
    const float* __restrict__ W, int ldw,
    const float* __restrict__ bias,
    _Float16* __restrict__ Y, int ldy, int K)
{
    constexpr int BK = 64;
    constexpr int FM = BM / 32;
    constexpr int FN = BN / 32;
    constexpr int AI = BM * 8 / 256;
    constexpr int BI = BN * 8 / 256;

    _Float16* As = lds;
    _Float16* Bs = lds + BM * BK;

    const int tid  = threadIdx.x;
    const int lane = tid & 63;
    const int wave = tid >> 6;
    const int wm   = wave >> 1;
    const int wn   = wave & 1;
    const int q    = lane >> 4;
    const int r16  = lane & 15;

    f32x4 acc[FM][FN] = {};

    for (int k0 = 0; k0 < K; k0 += BK) {
#pragma unroll
        for (int i = 0; i < AI; ++i) {
            int S = i * 256 + tid;
            int row = S >> 3, c = S & 7;
            const float* src = X + (size_t)(bm + row) * ldx + k0 + c * 8;
            float4 v0 = *(const float4*)src;
            float4 v1 = *(const float4*)(src + 4);
            half8 h = { (_Float16)v0.x, (_Float16)v0.y, (_Float16)v0.z, (_Float16)v0.w,
                        (_Float16)v1.x, (_Float16)v1.y, (_Float16)v1.z, (_Float16)v1.w };
            *(half8*)(As + row * BK + ((c ^ (row & 7)) * 8)) = h;
        }
#pragma unroll
        for (int j = 0; j < BI; ++j) {
            int S = j * 256 + tid;
            int row = S >> 3, c = S & 7;
            const float* src = W + (size_t)(bn + row) * ldw + k0 + c * 8;
            float4 v0 = *(const float4*)src;
            float4 v1 = *(const float4*)(src + 4);
            half8 h = { (_Float16)v0.x, (_Float16)v0.y, (_Float16)v0.z, (_Float16)v0.w,
                        (_Float16)v1.x, (_Float16)v1.y, (_Float16)v1.z, (_Float16)v1.w };
            *(half8*)(Bs + row * BK + ((c ^ (row & 7)) * 8)) = h;
        }
        __syncthreads();

#pragma unroll
        for (int s = 0; s < 2; ++s) {
            half8 a[FM], b[FN];
#pragma unroll
            for (int i = 0; i < FM; ++i) {
                int R = wm * (BM / 2) + i * 16 + r16;
                int sl = (s * 4 + q) ^ (R & 7);
                a[i] = *(const half8*)(As + R * BK + sl * 8);
            }
#pragma unroll
            for (int j = 0; j < FN; ++j) {
                int R = wn * (BN / 2) + j * 16 + r16;
                int sl = (s * 4 + q) ^ (R & 7);
                b[j] = *(const half8*)(Bs + R * BK + sl * 8);
            }
#pragma unroll
            for (int i = 0; i < FM; ++i)
#pragma unroll
                for (int j = 0; j < FN; ++j)
                    acc[i][j] = __builtin_amdgcn_mfma_f32_16x16x32_f16(
                        a[i], b[j], acc[i][j], 0, 0, 0);
        }
        __syncthreads();
    }

#pragma unroll
    for (int i = 0; i < FM; ++i) {
        const int m0 = bm + wm * (BM / 2) + i * 16 + q * 4;
#pragma unroll
        for (int j = 0; j < FN; ++j) {
            const int n = bn + wn * (BN / 2) + j * 16 + r16;
            const float bv = bias[n];
#pragma unroll
            for (int e = 0; e < 4; ++e) {
                float o = acc[i][j][e] + bv;
                if (RELU) o = fmaxf(o, 0.f);
                Y[(size_t)(m0 + e) * ldy + n] = (_Float16)o;
            }
        }
    }
}

// ---------------------------------------------------------------------------
// EmbeddingBag body: wave w = table w; float4/lane, 2 rows per instruction.
// ---------------------------------------------------------------------------
__device__ __forceinline__ void emb_body(
    int bag,
    const float* __restrict__ tables,
    const int*   __restrict__ idx,
    _Float16*    __restrict__ feat)
{
    const int wave = threadIdx.x >> 6;
    const int lane = threadIdx.x & 63;
    const int l5   = lane >> 5;
    const int c    = lane & 31;

    const int my_idx = idx[((size_t)bag * L_LOOK + lane) * NT + wave];
    const float* tab = tables + (size_t)wave * V_ROWS * D_EMB;

    float4 acc = {0.f, 0.f, 0.f, 0.f};
#pragma unroll 16
    for (int j = 0; j < 32; ++j) {
        int r = __shfl(my_idx, 2 * j + l5, 64);
        float4 v = ((const float4*)(tab + (size_t)r * D_EMB))[c];
        acc.x += v.x; acc.y += v.y; acc.z += v.z; acc.w += v.w;
    }
    acc.x += __shfl_xor(acc.x, 32, 64);
    acc.y += __shfl_xor(acc.y, 32, 64);
    acc.z += __shfl_xor(acc.z, 32, 64);
    acc.w += __shfl_xor(acc.w, 32, 64);
    if (l5 == 0) {
        half4 h = { (_Float16)acc.x, (_Float16)acc.y, (_Float16)acc.z, (_Float16)acc.w };
        *(half4*)(feat + (size_t)bag * FEAT + D_EMB + wave * D_EMB + c * 4) = h;
    }
}

// ---------------------------------------------------------------------------
// Generic fused dispatch: gemm tiles | emb bags (fp16 gemm path).
// __launch_bounds__(256,4): 4 blocks/CU for deeper gather concurrency.
// ---------------------------------------------------------------------------
struct GD {
    const _Float16* X; const _Float16* W; const float* bias; _Float16* Y;
    int ldx, ldw, ldy, K, m0, mTiles;
};

__global__ __launch_bounds__(256, 4) void mega(
    GD gA, int nA,
    int embBase, int embCount,
    const float* __restrict__ tables, const int* __restrict__ idx,
    _Float16* __restrict__ feat)
{
    __shared__ __align__(16) _Float16 lds[(128 + 128) * 64];
    int bid = blockIdx.x;
    if (bid < nA) {
        gemm_body<128, 128, true>(lds, gA.m0 + (bid % gA.mTiles) * 128,
                                  (bid / gA.mTiles) * 128,
                                  gA.X, gA.ldx, gA.W, gA.ldw, gA.bias,
                                  gA.Y, gA.ldy, gA.K);
        return;
    }
    bid -= nA;
    emb_body(embBase + bid, tables, idx, feat);
}

// ---------------------------------------------------------------------------
// D1: gemm1 (fp32 inputs, 256 tiles) + cvt of weights + emb bags.
// ---------------------------------------------------------------------------
struct CvtRest {
    const float* src[5];
    _Float16*    dst[5];
    int          n4[5];
};

__global__ __launch_bounds__(256, 4) void fused1(
    const float* __restrict__ X, const float* __restrict__ W,
    const float* __restrict__ bias, _Float16* __restrict__ Y,
    CvtRest cvt,
    const float* __restrict__ tables, const int* __restrict__ idx,
    _Float16* __restrict__ feat)
{
    __shared__ __align__(16) _Float16 lds[(128 + 128) * 64];
    int bid = blockIdx.x;
    if (bid < 256) {
        gemm_body_f32<128, 128, true>(lds, (bid & 31) * 128, (bid >> 5) * 128,
                                      X, 512, W, 512, bias, Y, 1024, 512);
        return;
    }
    bid -= 256;
    if (bid < 64) {
        const int t0 = bid * 256 + threadIdx.x;
        const int stride = 64 * 256;
#pragma unroll
        for (int t = 0; t < 5; ++t) {
            const float4* s = (const float4*)cvt.src[t];
            half4* d = (half4*)cvt.dst[t];
            for (int i = t0; i < cvt.n4[t]; i += stride) {
                float4 v = s[i];
                half4 h = { (_Float16)v.x, (_Float16)v.y, (_Float16)v.z, (_Float16)v.w };
                d[i] = h;
            }
        }
        return;
    }
    emb_body(bid - 64, tables, idx, feat);
}

// ---------------------------------------------------------------------------
// Plain GEMM dispatch (top MLP). BM x BN template tiles. Kept at 3 blocks/CU
// to protect register allocation (tail GEMMs are latency-critical).
// ---------------------------------------------------------------------------
template<int BM, int BN, bool RELU>
__global__ __launch_bounds__(256, 3) void gemm_h(
    const _Float16* __restrict__ X, int ldx,
    const _Float16* __restrict__ W, int ldw,
    const float* __restrict__ bias,
    _Float16* __restrict__ Y, int ldy,
    int K)
{
    __shared__ __align__(16) _Float16 lds[(BM + BN) * 64];
    gemm_body<BM, BN, RELU>(lds, blockIdx.y * BM, blockIdx.x * BN,
                            X, ldx, W, ldw, bias, Y, ldy, K);
}

// ---------------------------------------------------------------------------
// Final layer: out[m] = sigmoid(dot(z1[m,:512], w) + b), fp16 inputs.
// ---------------------------------------------------------------------------
__global__ __launch_bounds__(256) void top2_h(
    const _Float16* __restrict__ Z,
    const _Float16* __restrict__ w,
    const float* __restrict__ bsc,
    float* __restrict__ out)
{
    const int row  = blockIdx.x * 4 + (threadIdx.x >> 6);
    const int lane = threadIdx.x & 63;

    half8 z  = *(const half8*)(Z + (size_t)row * 512 + lane * 8);
    half8 wv = *(const half8*)(w + lane * 8);
    float s = 0.f;
#pragma unroll
    for (int i = 0; i < 8; ++i) s += (float)z[i] * (float)wv[i];
#pragma unroll
    for (int off = 32; off > 0; off >>= 1) s += __shfl_down(s, off, 64);
    if (lane == 0) {
        float x = s + bsc[0];
        out[row] = 1.f / (1.f + expf(-x));
    }
}

// ---------------------------------------------------------------------------
extern "C" void kernel_launch(void* const* d_in, const int* in_sizes, int n_in,
                              void* d_out, int out_size, void* d_ws, size_t ws_size,
                              hipStream_t stream) {
    const float* x_dense = (const float*)d_in[0];   // [4096,512]
    const float* tables  = (const float*)d_in[1];   // [4,500000,128]
    const float* bw0 = (const float*)d_in[2];
    const float* bb0 = (const float*)d_in[3];
    const float* bw1 = (const float*)d_in[4];
    const float* bb1 = (const float*)d_in[5];
    const float* bw2 = (const float*)d_in[6];
    const float* bb2 = (const float*)d_in[7];
    const float* tw0 = (const float*)d_in[8];
    const float* tb0 = (const float*)d_in[9];
    const float* tw1 = (const float*)d_in[10];
    const float* tb1 = (const float*)d_in[11];
    const float* tw2 = (const float*)d_in[12];
    const float* tb2 = (const float*)d_in[13];
    const int*   x_idx = (const int*)d_in[14];
    float* out = (float*)d_out;

    char* p = (char*)d_ws;
    auto alloc = [&](size_t bytes) {
        char* r = p; p += (bytes + 255) & ~(size_t)255; return r;
    };
    _Float16* bw1h = (_Float16*)alloc((size_t)512 * 1024 * 2);
    _Float16* bw2h = (_Float16*)alloc((size_t)128 * 512 * 2);
    _Float16* tw0h = (_Float16*)alloc((size_t)1024 * 640 * 2);
    _Float16* tw1h = (_Float16*)alloc((size_t)512 * 1024 * 2);
    _Float16* tw2h = (_Float16*)alloc((size_t)512 * 2);
    _Float16* h0h  = (_Float16*)alloc((size_t)4096 * 1024 * 2);
    _Float16* h1h  = (_Float16*)alloc((size_t)4096 * 512 * 2);
    _Float16* feat = (_Float16*)alloc((size_t)4096 * 640 * 2);
    _Float16* z0h  = (_Float16*)alloc((size_t)4096 * 1024 * 2);
    _Float16* z1h  = (_Float16*)alloc((size_t)4096 * 512 * 2);

    CvtRest cr;
    cr.src[0] = bw1; cr.dst[0] = bw1h; cr.n4[0] = 512 * 1024 / 4;
    cr.src[1] = bw2; cr.dst[1] = bw2h; cr.n4[1] = 128 * 512 / 4;
    cr.src[2] = tw0; cr.dst[2] = tw0h; cr.n4[2] = 1024 * 640 / 4;
    cr.src[3] = tw1; cr.dst[3] = tw1h; cr.n4[3] = 512 * 1024 / 4;
    cr.src[4] = tw2; cr.dst[4] = tw2h; cr.n4[4] = 512 / 4;

    dim3 blk(256);

    // ---- GEMM descriptors ----
    GD g2;  // h0 @ bw1^T -> h1 [4096,512]
    g2.X = h0h; g2.W = bw1h; g2.bias = bb1; g2.Y = h1h;
    g2.ldx = 1024; g2.ldw = 1024; g2.ldy = 512; g2.K = 1024; g2.m0 = 0; g2.mTiles = 32;

    GD g3;  // h1 @ bw2^T -> feat[:,0:128]
    g3.X = h1h; g3.W = bw2h; g3.bias = bb2; g3.Y = feat;
    g3.ldx = 512; g3.ldw = 512; g3.ldy = 640; g3.K = 512; g3.m0 = 0; g3.mTiles = 32;

    // ---- D1: gemm1(fp32 in) + cvt-rest + emb [0,2048) ----
    fused1<<<dim3(256 + 64 + 2048), blk, 0, stream>>>(
        x_dense, bw0, bb0, h0h, cr, tables, x_idx, feat);

    // ---- D2: gemm2 + emb [2048,3328) ----
    mega<<<dim3(128 + 1280), blk, 0, stream>>>(
        g2, 128, 2048, 1280, tables, x_idx, feat);

    // ---- D3: gemm3 + emb [3328,4096) ----
    mega<<<dim3(32 + 768), blk, 0, stream>>>(
        g3, 32, 3328, 768, tables, x_idx, feat);

    // ---- D4: feat @ tw0^T -> z0 [4096,1024]; 64x128 tiles -> 512 blocks ----
    gemm_h<64, 128, true><<<dim3(8, 64), blk, 0, stream>>>(
        feat, 640, tw0h, 640, tb0, z0h, 1024, 640);

    // ---- D5: z0 @ tw1^T -> z1 [4096,512]; 64x128 tiles -> 256 blocks ----
    gemm_h<64, 128, true><<<dim3(4, 64), blk, 0, stream>>>(
        z0h, 1024, tw1h, 1024, tb1, z1h, 512, 1024);

    // ---- D6: sigmoid(z1 . tw2 + tb2) ----
    top2_h<<<dim3(1024), blk, 0, stream>>>(z1h, tw2h, tb2, out);
}